// Round 7
// baseline (68.514 us; speedup 1.0000x reference)
//
#include <hip/hip_runtime.h>
#include <stdint.h>
#include <math.h>

#define N     500
#define DIN   100
#define DE    200
#define DOUT  100
#define AROW  (2*DIN + DE)        // 400
#define SLOPE 0.2f

#define JCH   2                   // j-chunks per row i
#define CROWS 250                 // 500 / 2
#define KP    512                 // Pbuf padded row length (j)
#define BK    720                 // Bcat row length: 512 (j) + 208 (d pad)
#define DEP   208                 // padded DE (f32 gsum stride)
#define GZF   104000              // 500*208 floats to zero

typedef __attribute__((ext_vector_type(8)))  short short8;
typedef __attribute__((ext_vector_type(16))) float f32x16;

static __device__ __forceinline__ unsigned short f2bf(float f) {
  union { float f; uint32_t u; } v; v.f = f;
  uint32_t r = (v.u + 0x7FFFu + ((v.u >> 16) & 1u)) >> 16;   // RNE
  return (unsigned short)r;
}

// ---------- K1: merged setup ----------
__global__ __launch_bounds__(256)
void setup_kernel(const float* __restrict__ R, const float* __restrict__ A,
                  const float* __restrict__ a2,
                  float* __restrict__ src, float* __restrict__ ssrc,
                  float* __restrict__ sdst, float* __restrict__ wv,
                  unsigned short* __restrict__ Bcat, unsigned short* __restrict__ Pbuf,
                  float* __restrict__ gsum, float* __restrict__ Zsum) {
  int b = blockIdx.x, t = threadIdx.x;
  if (b < N) {
    int i = b;
    __shared__ float rrow[DIN];
    __shared__ float sred[4];
    if (t < DIN) rrow[t] = R[i * DIN + t];
    if (t < KP - N) Pbuf[i * KP + N + t] = 0;          // zero j-pad 500..511
    __syncthreads();
    int o = -1; bool isSrc = false;
    if (t < DOUT) { o = t; isSrc = true; }
    else if (t >= 128 && t < 128 + DOUT) { o = t - 128; }
    float val = 0.f;
    if (o >= 0) {
      const float* arow = A + o * AROW + (isSrc ? 0 : DIN);
      #pragma unroll 4
      for (int d = 0; d < DIN; ++d) val += rrow[d] * arow[d];
      if (isSrc) src[i * DOUT + o] = val;
      else       Bcat[o * BK + i] = f2bf(val);         // B[k=j=i][n=o] = dst[j,o]
    }
    float red = (o >= 0) ? val * a2[o] : 0.f;
    #pragma unroll
    for (int k = 1; k < 64; k <<= 1) red += __shfl_xor(red, k, 64);
    if ((t & 63) == 0) sred[t >> 6] = red;
    __syncthreads();
    if (t == 0)   ssrc[i] = sred[0] + sred[1];
    if (t == 128) sdst[i] = sred[2] + sred[3];
  } else if (b == N) {
    if (t < DE) {
      float s = 0.f;
      for (int o = 0; o < DOUT; ++o) s += A[o * AROW + 2 * DIN + t] * a2[o];
      wv[t] = s;
    }
  } else if (b <= N + DOUT) {
    int o = b - (N + 1);
    if (t < DE) Bcat[o * BK + KP + t] = f2bf(A[o * AROW + 2 * DIN + t]);
    if (t < KP - N) Bcat[o * BK + N + t] = 0;                                 // j-pad
    if (t >= 32 && t < 32 + (BK - KP - DE)) Bcat[o * BK + KP + DE + (t - 32)] = 0; // d-pad
  } else if (b <= 702) {
    int off = (b - 601) * 1024 + t * 4;
    if (off < GZF) *(float4*)(gsum + off) = make_float4(0.f, 0.f, 0.f, 0.f);
  } else {
    if (t < 125) *(float4*)(Zsum + t * 4) = make_float4(0.f, 0.f, 0.f, 0.f);
  }
}

// ---------- K2: two-phase streaming pass (no cross-lane reduce) ----------
__global__ __launch_bounds__(256, 4)
void passA(const float* __restrict__ E, const int* __restrict__ adj,
           const float* __restrict__ ssrcA, const float* __restrict__ sdstA,
           const float* __restrict__ wv,
           unsigned short* __restrict__ Pbuf,
           float* __restrict__ gsum, float* __restrict__ Zsum) {
  __shared__ int   list[CROWS + 8];
  __shared__ float bias[CROWS + 8];
  __shared__ float parr[CROWS + 8];
  __shared__ float wls[200];
  __shared__ int cntS;
  __shared__ float gl[4][200];
  __shared__ float zl[4];

  int bid = blockIdx.x;
  int i = bid >> 1, c = bid & 1;
  int jbeg = c * CROWS;
  int t = threadIdx.x, wid = t >> 6, lane = t & 63;

  if (t == 0) cntS = 0;
  if (t < 200) wls[t] = wv[t];
  __syncthreads();

  float ssrc_i = ssrcA[i];
  // ballot-compact active j's; write p=0 for inactive
  bool active = false;
  if (t < CROWS) active = (adj[(size_t)i * N + jbeg + t] > 0);
  unsigned long long mask = __ballot(active);
  int wbase = 0;
  if (lane == 0 && mask) wbase = atomicAdd(&cntS, __popcll(mask));
  wbase = __shfl(wbase, 0);
  if (active) {
    int slot = wbase + __popcll(mask & ((1ull << lane) - 1ull));
    list[slot] = jbeg + t;
    bias[slot] = ssrc_i + sdstA[jbeg + t];
  } else if (t < CROWS) {
    Pbuf[i * KP + jbeg + t] = 0;
  }
  __syncthreads();
  int cnt = cntS;

  // per-wave slot range (<= 63 slots, one lane each)
  int per = (cnt + 3) >> 2;
  int lo = wid * per;
  int hi = lo + per; if (hi > cnt) hi = cnt;
  const float* Erow = E + (size_t)i * N * DE;

  // ---- pass 1: lane-per-row private dot + score + p ----
  float pz = 0.f;                      // this lane's p (for Z reduce)
  {
    int s = lo + lane;
    if (s < hi) {
      int j = list[s];
      const float* rp = Erow + (size_t)j * DE;
      float a0 = 0.f, a1 = 0.f, a2v = 0.f, a3 = 0.f;
      #pragma unroll 10
      for (int d4 = 0; d4 < 50; ++d4) {
        float4 ev = *(const float4*)(rp + d4 * 4);
        float4 wf = *(const float4*)(&wls[d4 * 4]);
        a0  += ev.x * wf.x; a1 += ev.y * wf.y;
        a2v += ev.z * wf.z; a3 += ev.w * wf.w;
      }
      float sc = bias[s] + ((a0 + a1) + (a2v + a3));
      sc = sc > 0.f ? sc : SLOPE * sc;
      pz = __expf(sc);
      parr[s] = pz;
      Pbuf[i * KP + j] = f2bf(pz);
    }
  }
  // Z: one shuffle-tree per wave (amortized over all rows)
  float Zw = pz;
  #pragma unroll
  for (int k = 1; k < 64; k <<= 1) Zw += __shfl_xor(Zw, k);

  // ---- pass 2: lane-per-d g accumulation over own rows (L1/L2-hot) ----
  float4 g = make_float4(0.f, 0.f, 0.f, 0.f);
  int s2 = lo;
  for (; s2 + 3 < hi; s2 += 4) {
    int j0 = list[s2], j1 = list[s2 + 1], j2 = list[s2 + 2], j3 = list[s2 + 3];
    float p0 = parr[s2], p1 = parr[s2 + 1], p2 = parr[s2 + 2], p3 = parr[s2 + 3];
    if (lane < 50) {
      float4 e0 = *(const float4*)(Erow + (size_t)j0 * DE + lane * 4);
      float4 e1 = *(const float4*)(Erow + (size_t)j1 * DE + lane * 4);
      float4 e2 = *(const float4*)(Erow + (size_t)j2 * DE + lane * 4);
      float4 e3 = *(const float4*)(Erow + (size_t)j3 * DE + lane * 4);
      g.x += p0 * e0.x + p1 * e1.x + p2 * e2.x + p3 * e3.x;
      g.y += p0 * e0.y + p1 * e1.y + p2 * e2.y + p3 * e3.y;
      g.z += p0 * e0.z + p1 * e1.z + p2 * e2.z + p3 * e3.z;
      g.w += p0 * e0.w + p1 * e1.w + p2 * e2.w + p3 * e3.w;
    }
  }
  for (; s2 < hi; ++s2) {
    int j = list[s2];
    float p = parr[s2];
    if (lane < 50) {
      float4 ev = *(const float4*)(Erow + (size_t)j * DE + lane * 4);
      g.x += p * ev.x; g.y += p * ev.y; g.z += p * ev.z; g.w += p * ev.w;
    }
  }

  // block-reduce g, Z; atomically fold into per-row sums
  if (lane < 50) *(float4*)&gl[wid][lane * 4] = g;
  if (lane == 0) zl[wid] = Zw;
  __syncthreads();
  if (t < 200) {
    float s = gl[0][t] + gl[1][t] + gl[2][t] + gl[3][t];
    atomicAdd(gsum + (size_t)i * DEP + t, s);
  }
  if (t == 200) atomicAdd(Zsum + i, zl[0] + zl[1] + zl[2] + zl[3]);
}

// ---------- K3: combine — [P | g] @ [dst ; a_ent^T] via MFMA ----------
// 64 blocks x 64 threads: one wave per (i-tile, o-wave)
__global__ __launch_bounds__(64)
void combine_kernel(const float* __restrict__ src,
                    const unsigned short* __restrict__ Pbuf,
                    const unsigned short* __restrict__ Bcat,
                    const float* __restrict__ gsum,
                    const float* __restrict__ Zsum,
                    float* __restrict__ out) {
  int b = blockIdx.x;
  int i0 = (b >> 2) * 32;
  int ow = b & 3;
  int t = threadIdx.x;                  // 0..63
  int c31 = t & 31, hi = t >> 5;
  int o = ow * 32 + c31;
  int arow = i0 + c31; if (arow > N - 1) arow = N - 1;

  const unsigned short* Prow = Pbuf + (size_t)arow * KP;
  const float* grow = gsum + (size_t)arow * DEP;

  f32x16 acc = {};
  #pragma unroll
  for (int ks = 0; ks < 45; ++ks) {
    short8 a, bf;
    if (ks < 32) {
      a = *(const short8*)(Prow + ks * 16 + hi * 8);
    } else {
      int d0 = (ks - 32) * 16 + hi * 8;
      float4 ga = *(const float4*)(grow + d0);
      float4 gb = *(const float4*)(grow + d0 + 4);
      a[0] = (short)f2bf(ga.x); a[1] = (short)f2bf(ga.y);
      a[2] = (short)f2bf(ga.z); a[3] = (short)f2bf(ga.w);
      a[4] = (short)f2bf(gb.x); a[5] = (short)f2bf(gb.y);
      a[6] = (short)f2bf(gb.z); a[7] = (short)f2bf(gb.w);
    }
    if (o < DOUT) bf = *(const short8*)(Bcat + (size_t)o * BK + ks * 16 + hi * 8);
    else { short8 zz = {}; bf = zz; }
    acc = __builtin_amdgcn_mfma_f32_32x32x16_bf16(a, bf, acc, 0, 0, 0);
  }

  if (o < DOUT) {
    #pragma unroll
    for (int r = 0; r < 16; ++r) {
      int row = (r & 3) + 8 * (r >> 2) + 4 * hi;
      int i = i0 + row;
      if (i < N) {
        float h = src[i * DOUT + o] + acc[r] / Zsum[i];
        out[i * DOUT + o] = h > 0.f ? h : expm1f(h);
      }
    }
  }
}

extern "C" void kernel_launch(void* const* d_in, const int* in_sizes, int n_in,
                              void* d_out, int out_size, void* d_ws, size_t ws_size,
                              hipStream_t stream) {
  const float* R   = (const float*)d_in[0];
  const float* E   = (const float*)d_in[1];
  const int*   adj = (const int*)d_in[2];
  const float* A   = (const float*)d_in[3];
  const float* a2  = (const float*)d_in[4];
  float* out = (float*)d_out;

  char* wsb = (char*)d_ws;
  float*          src  = (float*)(wsb + 0);                // 200,000 B
  float*          ssrc = (float*)(wsb + 200000);           //   2,000 B
  float*          sdst = (float*)(wsb + 202000);           //   2,000 B
  float*          wv   = (float*)(wsb + 204000);           //     800 B
  unsigned short* Bcat = (unsigned short*)(wsb + 204800);  // 144,000 B
  unsigned short* Pbuf = (unsigned short*)(wsb + 348800);  // 512,000 B
  float*          gsum = (float*)(wsb + 860800);           // 416,000 B (f32, atomic)
  float*          Zsum = (float*)(wsb + 1276800);          //   2,000 B

  setup_kernel<<<704, 256, 0, stream>>>(R, A, a2, src, ssrc, sdst, wv, Bcat, Pbuf, gsum, Zsum);
  passA<<<N * JCH, 256, 0, stream>>>(E, adj, ssrc, sdst, wv, Pbuf, gsum, Zsum);
  combine_kernel<<<64, 64, 0, stream>>>(src, Pbuf, Bcat, gsum, Zsum, out);
}

// Round 8
// 57.030 us; speedup vs baseline: 1.2014x; 1.2014x over previous
//
#include <hip/hip_runtime.h>
#include <stdint.h>
#include <math.h>

#define N     500
#define DIN   100
#define DE    200
#define DOUT  100
#define AROW  (2*DIN + DE)        // 400
#define SLOPE 0.2f

#define JCH   2                   // j-chunks per row i
#define CROWS 250                 // 500 / 2
#define KP    512                 // Pbuf padded row length (j)
#define BK    720                 // Bcat row length: 512 (j) + 208 (d pad)
#define DEP   208                 // padded DE (f32 gsum stride)
#define GZF   104000              // 500*208 floats to zero

typedef __attribute__((ext_vector_type(8)))  short short8;
typedef __attribute__((ext_vector_type(16))) float f32x16;

static __device__ __forceinline__ unsigned short f2bf(float f) {
  union { float f; uint32_t u; } v; v.f = f;
  uint32_t r = (v.u + 0x7FFFu + ((v.u >> 16) & 1u)) >> 16;   // RNE
  return (unsigned short)r;
}

// ---------- K1: merged setup ----------
__global__ __launch_bounds__(256)
void setup_kernel(const float* __restrict__ R, const float* __restrict__ A,
                  const float* __restrict__ a2,
                  float* __restrict__ src, float* __restrict__ ssrc,
                  float* __restrict__ sdst, float* __restrict__ wv,
                  unsigned short* __restrict__ Bcat, unsigned short* __restrict__ Pbuf,
                  float* __restrict__ gsum, float* __restrict__ Zsum) {
  int b = blockIdx.x, t = threadIdx.x;
  if (b < N) {
    int i = b;
    __shared__ float rrow[DIN];
    __shared__ float sred[4];
    if (t < DIN) rrow[t] = R[i * DIN + t];
    if (t < KP - N) Pbuf[i * KP + N + t] = 0;          // zero j-pad 500..511
    __syncthreads();
    int o = -1; bool isSrc = false;
    if (t < DOUT) { o = t; isSrc = true; }
    else if (t >= 128 && t < 128 + DOUT) { o = t - 128; }
    float val = 0.f;
    if (o >= 0) {
      const float* arow = A + o * AROW + (isSrc ? 0 : DIN);
      #pragma unroll 4
      for (int d = 0; d < DIN; ++d) val += rrow[d] * arow[d];
      if (isSrc) src[i * DOUT + o] = val;
      else       Bcat[o * BK + i] = f2bf(val);         // B[k=j=i][n=o] = dst[j,o]
    }
    float red = (o >= 0) ? val * a2[o] : 0.f;
    #pragma unroll
    for (int k = 1; k < 64; k <<= 1) red += __shfl_xor(red, k, 64);
    if ((t & 63) == 0) sred[t >> 6] = red;
    __syncthreads();
    if (t == 0)   ssrc[i] = sred[0] + sred[1];
    if (t == 128) sdst[i] = sred[2] + sred[3];
  } else if (b == N) {
    if (t < DE) {
      float s = 0.f;
      for (int o = 0; o < DOUT; ++o) s += A[o * AROW + 2 * DIN + t] * a2[o];
      wv[t] = s;
    }
  } else if (b <= N + DOUT) {
    int o = b - (N + 1);
    if (t < DE) Bcat[o * BK + KP + t] = f2bf(A[o * AROW + 2 * DIN + t]);
    if (t < KP - N) Bcat[o * BK + N + t] = 0;                                 // j-pad
    if (t >= 32 && t < 32 + (BK - KP - DE)) Bcat[o * BK + KP + DE + (t - 32)] = 0; // d-pad
  } else if (b <= 702) {
    int off = (b - 601) * 1024 + t * 4;
    if (off < GZF) *(float4*)(gsum + off) = make_float4(0.f, 0.f, 0.f, 0.f);
  } else {
    if (t < 125) *(float4*)(Zsum + t * 4) = make_float4(0.f, 0.f, 0.f, 0.f);
  }
}

// ---------- K2: streaming pass over E (compacted list, unroll-8, SW-pipelined) ----------
#define LOADBUF(EV, BB) do {                                               \
    if (lane < 50) {                                                       \
      _Pragma("unroll")                                                    \
      for (int r = 0; r < 8; ++r) {                                        \
        int j_ = list[(BB) + r];                                           \
        EV[r] = *(const float4*)(Erow + (size_t)j_ * DE + lane * 4);       \
      }                                                                    \
    }                                                                      \
  } while (0)

#define COMPUTE(EV, BB) do {                                               \
    float d_[8];                                                           \
    _Pragma("unroll")                                                      \
    for (int r = 0; r < 8; ++r)                                            \
      d_[r] = EV[r].x * w4.x + EV[r].y * w4.y + EV[r].z * w4.z + EV[r].w * w4.w; \
    _Pragma("unroll")                                                      \
    for (int k = 1; k < 64; k <<= 1) {                                     \
      _Pragma("unroll")                                                    \
      for (int r = 0; r < 8; ++r) d_[r] += __shfl_xor(d_[r], k);           \
    }                                                                      \
    float p_[8]; float za_ = 0.f;                                          \
    _Pragma("unroll")                                                      \
    for (int r = 0; r < 8; ++r) {                                          \
      float s_ = bias[(BB) + r] + d_[r];                                   \
      s_ = s_ > 0.f ? s_ : SLOPE * s_;                                     \
      p_[r] = __expf(s_); za_ += p_[r];                                    \
    }                                                                      \
    Z += za_;                                                              \
    _Pragma("unroll")                                                      \
    for (int r = 0; r < 8; ++r) {                                          \
      g.x += p_[r] * EV[r].x; g.y += p_[r] * EV[r].y;                      \
      g.z += p_[r] * EV[r].z; g.w += p_[r] * EV[r].w;                      \
    }                                                                      \
    if (lane == 0) {                                                       \
      _Pragma("unroll")                                                    \
      for (int r = 0; r < 8; ++r) Pbuf[i * KP + list[(BB) + r]] = f2bf(p_[r]); \
    }                                                                      \
  } while (0)

__global__ __launch_bounds__(256, 4)
void passA(const float* __restrict__ E, const int* __restrict__ adj,
           const float* __restrict__ ssrcA, const float* __restrict__ sdstA,
           const float* __restrict__ wv,
           unsigned short* __restrict__ Pbuf,
           float* __restrict__ gsum, float* __restrict__ Zsum) {
  __shared__ int list[CROWS + 8];
  __shared__ float bias[CROWS + 8];     // ssrc_i + sdst[j] per compacted slot
  __shared__ int cntS;
  __shared__ float gl[4][200];
  __shared__ float zl[4];

  int bid = blockIdx.x;
  int i = bid >> 1, c = bid & 1;
  int jbeg = c * CROWS;
  int t = threadIdx.x, wid = t >> 6, lane = t & 63;

  if (t == 0) cntS = 0;
  __syncthreads();

  float ssrc_i = ssrcA[i];
  // ballot-compact active j's; write p=0 for inactive
  bool active = false;
  if (t < CROWS) active = (adj[(size_t)i * N + jbeg + t] > 0);
  unsigned long long mask = __ballot(active);
  int wbase = 0;
  if (lane == 0 && mask) wbase = atomicAdd(&cntS, __popcll(mask));
  wbase = __shfl(wbase, 0);
  if (active) {
    int slot = wbase + __popcll(mask & ((1ull << lane) - 1ull));
    list[slot] = jbeg + t;
    bias[slot] = ssrc_i + sdstA[jbeg + t];
  } else if (t < CROWS) {
    Pbuf[i * KP + jbeg + t] = 0;
  }
  __syncthreads();
  int cnt = cntS;

  float4 w4 = make_float4(0.f, 0.f, 0.f, 0.f);
  if (lane < 50) w4 = *(const float4*)(wv + lane * 4);
  float4 g = make_float4(0.f, 0.f, 0.f, 0.f);
  float Z = 0.f;
  const float* Erow = E + (size_t)i * N * DE;

  // software-pipelined main loop: 8 rows/wave/iter, double-buffered registers
  float4 evA[8], evB[8];
  #pragma unroll
  for (int r = 0; r < 8; ++r) {
    evA[r] = make_float4(0.f, 0.f, 0.f, 0.f);
    evB[r] = make_float4(0.f, 0.f, 0.f, 0.f);
  }
  int base = wid * 8;
  if (base + 7 < cnt) {
    LOADBUF(evA, base);
    for (;;) {
      int nb = base + 32;
      if (nb + 7 < cnt) LOADBUF(evB, nb);
      COMPUTE(evA, base);
      base = nb;
      if (!(base + 7 < cnt)) break;
      nb = base + 32;
      if (nb + 7 < cnt) LOADBUF(evA, nb);
      COMPUTE(evB, base);
      base = nb;
      if (!(base + 7 < cnt)) break;
    }
  }
  // tail: remaining < 8 entries, one row per wave round-robin
  for (int idx = (cnt & ~7) + wid; idx < cnt; idx += 4) {
    int j = list[idx];
    float bi = bias[idx];
    float4 ev = make_float4(0.f, 0.f, 0.f, 0.f);
    if (lane < 50) ev = *(const float4*)(Erow + (size_t)j * DE + lane * 4);
    float d = ev.x * w4.x + ev.y * w4.y + ev.z * w4.z + ev.w * w4.w;
    #pragma unroll
    for (int k = 1; k < 64; k <<= 1) d += __shfl_xor(d, k);
    float s = bi + d; s = s > 0.f ? s : SLOPE * s;
    float p = __expf(s);
    Z += p;
    g.x += p * ev.x; g.y += p * ev.y; g.z += p * ev.z; g.w += p * ev.w;
    if (lane == 0) Pbuf[i * KP + j] = f2bf(p);
  }

  // block-reduce g, Z; atomically fold into per-row sums
  if (lane < 50) *(float4*)&gl[wid][lane * 4] = g;
  if (lane == 0) zl[wid] = Z;
  __syncthreads();
  if (t < 200) {
    float s = gl[0][t] + gl[1][t] + gl[2][t] + gl[3][t];
    atomicAdd(gsum + (size_t)i * DEP + t, s);
  }
  if (t == 200) atomicAdd(Zsum + i, zl[0] + zl[1] + zl[2] + zl[3]);
}

// ---------- K3: combine — [P | g] @ [dst ; a_ent^T] via MFMA (dual acc chains) ----------
__global__ __launch_bounds__(64)
void combine_kernel(const float* __restrict__ src,
                    const unsigned short* __restrict__ Pbuf,
                    const unsigned short* __restrict__ Bcat,
                    const float* __restrict__ gsum,
                    const float* __restrict__ Zsum,
                    float* __restrict__ out) {
  int b = blockIdx.x;
  int i0 = (b >> 2) * 32;
  int ow = b & 3;
  int t = threadIdx.x;                  // 0..63
  int c31 = t & 31, hi = t >> 5;
  int o = ow * 32 + c31;
  int arow = i0 + c31; if (arow > N - 1) arow = N - 1;

  const unsigned short* Prow = Pbuf + (size_t)arow * KP;
  const float* grow = gsum + (size_t)arow * DEP;

  f32x16 acc0 = {}, acc1 = {};
  #pragma unroll
  for (int ks = 0; ks < 45; ++ks) {
    short8 a, bf;
    if (ks < 32) {
      a = *(const short8*)(Prow + ks * 16 + hi * 8);
    } else {
      int d0 = (ks - 32) * 16 + hi * 8;
      float4 ga = *(const float4*)(grow + d0);
      float4 gb = *(const float4*)(grow + d0 + 4);
      a[0] = (short)f2bf(ga.x); a[1] = (short)f2bf(ga.y);
      a[2] = (short)f2bf(ga.z); a[3] = (short)f2bf(ga.w);
      a[4] = (short)f2bf(gb.x); a[5] = (short)f2bf(gb.y);
      a[6] = (short)f2bf(gb.z); a[7] = (short)f2bf(gb.w);
    }
    if (o < DOUT) bf = *(const short8*)(Bcat + (size_t)o * BK + ks * 16 + hi * 8);
    else { short8 zz = {}; bf = zz; }
    if (ks & 1) acc1 = __builtin_amdgcn_mfma_f32_32x32x16_bf16(a, bf, acc1, 0, 0, 0);
    else        acc0 = __builtin_amdgcn_mfma_f32_32x32x16_bf16(a, bf, acc0, 0, 0, 0);
  }

  if (o < DOUT) {
    #pragma unroll
    for (int r = 0; r < 16; ++r) {
      int row = (r & 3) + 8 * (r >> 2) + 4 * hi;
      int i = i0 + row;
      if (i < N) {
        float h = src[i * DOUT + o] + (acc0[r] + acc1[r]) / Zsum[i];
        out[i * DOUT + o] = h > 0.f ? h : expm1f(h);
      }
    }
  }
}

extern "C" void kernel_launch(void* const* d_in, const int* in_sizes, int n_in,
                              void* d_out, int out_size, void* d_ws, size_t ws_size,
                              hipStream_t stream) {
  const float* R   = (const float*)d_in[0];
  const float* E   = (const float*)d_in[1];
  const int*   adj = (const int*)d_in[2];
  const float* A   = (const float*)d_in[3];
  const float* a2  = (const float*)d_in[4];
  float* out = (float*)d_out;

  char* wsb = (char*)d_ws;
  float*          src  = (float*)(wsb + 0);                // 200,000 B
  float*          ssrc = (float*)(wsb + 200000);           //   2,000 B
  float*          sdst = (float*)(wsb + 202000);           //   2,000 B
  float*          wv   = (float*)(wsb + 204000);           //     800 B
  unsigned short* Bcat = (unsigned short*)(wsb + 204800);  // 144,000 B
  unsigned short* Pbuf = (unsigned short*)(wsb + 348800);  // 512,000 B
  float*          gsum = (float*)(wsb + 860800);           // 416,000 B (f32, atomic)
  float*          Zsum = (float*)(wsb + 1276800);          //   2,000 B

  setup_kernel<<<704, 256, 0, stream>>>(R, A, a2, src, ssrc, sdst, wv, Bcat, Pbuf, gsum, Zsum);
  passA<<<N * JCH, 256, 0, stream>>>(E, adj, ssrc, sdst, wv, Pbuf, gsum, Zsum);
  combine_kernel<<<64, 64, 0, stream>>>(src, Pbuf, Bcat, gsum, Zsum, out);
}

// Round 9
// 53.806 us; speedup vs baseline: 1.2734x; 1.0599x over previous
//
#include <hip/hip_runtime.h>
#include <stdint.h>
#include <math.h>

#define N     500
#define DIN   100
#define DE    200
#define DOUT  100
#define AROW  (2*DIN + DE)        // 400
#define SLOPE 0.2f

#define JCH   2                   // j-chunks per row i
#define CROWS 250                 // 500 / 2
#define KP    512                 // Pbuf padded row length (j)
#define BK    720                 // Bcat row length: 512 (j) + 208 (d pad)
#define DEP   208                 // padded DE (f32 gsum stride)
#define GZF   104000              // 500*208 floats to zero

typedef __attribute__((ext_vector_type(8)))  short short8;
typedef __attribute__((ext_vector_type(16))) float f32x16;

static __device__ __forceinline__ unsigned short f2bf(float f) {
  union { float f; uint32_t u; } v; v.f = f;
  uint32_t r = (v.u + 0x7FFFu + ((v.u >> 16) & 1u)) >> 16;   // RNE
  return (unsigned short)r;
}

// ---------- K1: merged setup ----------
__global__ __launch_bounds__(256)
void setup_kernel(const float* __restrict__ R, const float* __restrict__ A,
                  const float* __restrict__ a2,
                  float* __restrict__ src, float* __restrict__ ssrc,
                  float* __restrict__ sdst, float* __restrict__ wv,
                  unsigned short* __restrict__ Bcat, unsigned short* __restrict__ Pbuf,
                  float* __restrict__ gsum, float* __restrict__ Zsum) {
  int b = blockIdx.x, t = threadIdx.x;
  if (b < N) {
    int i = b;
    __shared__ float rrow[DIN];
    __shared__ float sred[4];
    if (t < DIN) rrow[t] = R[i * DIN + t];
    if (t < KP - N) Pbuf[i * KP + N + t] = 0;          // zero j-pad 500..511
    __syncthreads();
    int o = -1; bool isSrc = false;
    if (t < DOUT) { o = t; isSrc = true; }
    else if (t >= 128 && t < 128 + DOUT) { o = t - 128; }
    float val = 0.f;
    if (o >= 0) {
      const float* arow = A + o * AROW + (isSrc ? 0 : DIN);
      #pragma unroll 4
      for (int d = 0; d < DIN; ++d) val += rrow[d] * arow[d];
      if (isSrc) src[i * DOUT + o] = val;
      else       Bcat[o * BK + i] = f2bf(val);         // B[k=j=i][n=o] = dst[j,o]
    }
    float red = (o >= 0) ? val * a2[o] : 0.f;
    #pragma unroll
    for (int k = 1; k < 64; k <<= 1) red += __shfl_xor(red, k, 64);
    if ((t & 63) == 0) sred[t >> 6] = red;
    __syncthreads();
    if (t == 0)   ssrc[i] = sred[0] + sred[1];
    if (t == 128) sdst[i] = sred[2] + sred[3];
  } else if (b == N) {
    if (t < DE) {
      float s = 0.f;
      for (int o = 0; o < DOUT; ++o) s += A[o * AROW + 2 * DIN + t] * a2[o];
      wv[t] = s;
    }
  } else if (b <= N + DOUT) {
    int o = b - (N + 1);
    if (t < DE) Bcat[o * BK + KP + t] = f2bf(A[o * AROW + 2 * DIN + t]);
    if (t < KP - N) Bcat[o * BK + N + t] = 0;                                 // j-pad
    if (t >= 32 && t < 32 + (BK - KP - DE)) Bcat[o * BK + KP + DE + (t - 32)] = 0; // d-pad
  } else if (b <= 702) {
    int off = (b - 601) * 1024 + t * 4;
    if (off < GZF) *(float4*)(gsum + off) = make_float4(0.f, 0.f, 0.f, 0.f);
  } else {
    if (t < 125) *(float4*)(Zsum + t * 4) = make_float4(0.f, 0.f, 0.f, 0.f);
  }
}

// ---------- K2: streaming pass, row-pair-per-wave (group-per-row) ----------
__global__ __launch_bounds__(256, 4)
void passA(const float* __restrict__ E, const int* __restrict__ adj,
           const float* __restrict__ ssrcA, const float* __restrict__ sdstA,
           const float* __restrict__ wv,
           unsigned short* __restrict__ Pbuf,
           float* __restrict__ gsum, float* __restrict__ Zsum) {
  __shared__ int   list[CROWS + 8];
  __shared__ float bias[CROWS + 8];     // ssrc_i + sdst[j] per compacted slot
  __shared__ int cntS;
  __shared__ float gl[4][200];
  __shared__ float zl[4];

  int bid = blockIdx.x;
  int i = bid >> 1, c = bid & 1;
  int jbeg = c * CROWS;
  int t = threadIdx.x, wid = t >> 6, lane = t & 63;
  int ll = lane & 31;                   // lane-in-group
  int grp = lane >> 5;                  // 0 = row A, 1 = row B

  if (t == 0) cntS = 0;
  __syncthreads();

  float ssrc_i = ssrcA[i];
  // ballot-compact active j's; write p=0 for inactive
  bool active = false;
  if (t < CROWS) active = (adj[(size_t)i * N + jbeg + t] > 0);
  unsigned long long mask = __ballot(active);
  int wbase = 0;
  if (lane == 0 && mask) wbase = atomicAdd(&cntS, __popcll(mask));
  wbase = __shfl(wbase, 0);
  if (active) {
    int slot = wbase + __popcll(mask & ((1ull << lane) - 1ull));
    list[slot] = jbeg + t;
    bias[slot] = ssrc_i + sdstA[jbeg + t];
  } else if (t < CROWS) {
    Pbuf[i * KP + jbeg + t] = 0;
  }
  __syncthreads();
  int cnt = cntS;
  int cnt_pad = (cnt + 7) & ~7;
  // pad with sentinels: valid row index, bias -> p = 0
  for (int s = cnt + t; s < cnt_pad; s += 256) { list[s] = jbeg; bias[s] = -1e30f; }
  __syncthreads();

  // per-lane w slice: elems [8ll .. 8ll+7]
  float4 wa = make_float4(0.f, 0.f, 0.f, 0.f), wb = wa;
  if (ll < 25) {
    wa = *(const float4*)(wv + ll * 8);
    wb = *(const float4*)(wv + ll * 8 + 4);
  }

  float g1x = 0.f, g1y = 0.f, g1z = 0.f, g1w = 0.f;   // elems 8ll+0..3
  float g2x = 0.f, g2y = 0.f, g2z = 0.f, g2w = 0.f;   // elems 8ll+4..7
  float Z = 0.f;
  const float* Erow = E + (size_t)i * N * DE;

  // main: 8 slots (4 row-pairs) per wave per iteration
  for (int base = wid * 8; base < cnt_pad; base += 32) {
    #pragma unroll
    for (int r = 0; r < 4; ++r) {
      int slot = base + 2 * r + grp;                  // per-lane: group picks row
      int j = list[slot];
      float bi = bias[slot];
      float4 ev1 = make_float4(0.f, 0.f, 0.f, 0.f), ev2 = ev1;
      if (ll < 25) {
        const float* rp = Erow + (size_t)j * DE + ll * 8;
        ev1 = *(const float4*)(rp);
        ev2 = *(const float4*)(rp + 4);
      }
      float d = ev1.x * wa.x + ev1.y * wa.y + ev1.z * wa.z + ev1.w * wa.w
              + ev2.x * wb.x + ev2.y * wb.y + ev2.z * wb.z + ev2.w * wb.w;
      d += __shfl_xor(d, 1);  d += __shfl_xor(d, 2);  d += __shfl_xor(d, 4);
      d += __shfl_xor(d, 8);  d += __shfl_xor(d, 16);      // uniform within group
      float s = bi + d;
      s = s > 0.f ? s : SLOPE * s;
      float p = __expf(s);                                 // 0 for sentinel slots
      Z += p;
      g1x += p * ev1.x; g1y += p * ev1.y; g1z += p * ev1.z; g1w += p * ev1.w;
      g2x += p * ev2.x; g2y += p * ev2.y; g2z += p * ev2.z; g2w += p * ev2.w;
      if (ll == 0 && slot < cnt) Pbuf[i * KP + j] = f2bf(p);
    }
  }

  // merge the two groups (A+B) once
  g1x += __shfl_xor(g1x, 32); g1y += __shfl_xor(g1y, 32);
  g1z += __shfl_xor(g1z, 32); g1w += __shfl_xor(g1w, 32);
  g2x += __shfl_xor(g2x, 32); g2y += __shfl_xor(g2y, 32);
  g2z += __shfl_xor(g2z, 32); g2w += __shfl_xor(g2w, 32);
  Z += __shfl_xor(Z, 32);

  if (lane < 25) {
    float* gp = &gl[wid][lane * 8];
    gp[0] = g1x; gp[1] = g1y; gp[2] = g1z; gp[3] = g1w;
    gp[4] = g2x; gp[5] = g2y; gp[6] = g2z; gp[7] = g2w;
  }
  if (lane == 0) zl[wid] = Z;
  __syncthreads();
  if (t < 200) {
    float s = gl[0][t] + gl[1][t] + gl[2][t] + gl[3][t];
    atomicAdd(gsum + (size_t)i * DEP + t, s);
  }
  if (t == 200) atomicAdd(Zsum + i, zl[0] + zl[1] + zl[2] + zl[3]);
}

// ---------- K3: combine — [P | g] @ [dst ; a_ent^T] via MFMA (dual acc chains) ----------
__global__ __launch_bounds__(64)
void combine_kernel(const float* __restrict__ src,
                    const unsigned short* __restrict__ Pbuf,
                    const unsigned short* __restrict__ Bcat,
                    const float* __restrict__ gsum,
                    const float* __restrict__ Zsum,
                    float* __restrict__ out) {
  int b = blockIdx.x;
  int i0 = (b >> 2) * 32;
  int ow = b & 3;
  int t = threadIdx.x;                  // 0..63
  int c31 = t & 31, hi = t >> 5;
  int o = ow * 32 + c31;
  int arow = i0 + c31; if (arow > N - 1) arow = N - 1;

  const unsigned short* Prow = Pbuf + (size_t)arow * KP;
  const float* grow = gsum + (size_t)arow * DEP;

  f32x16 acc0 = {}, acc1 = {};
  #pragma unroll
  for (int ks = 0; ks < 45; ++ks) {
    short8 a, bf;
    if (ks < 32) {
      a = *(const short8*)(Prow + ks * 16 + hi * 8);
    } else {
      int d0 = (ks - 32) * 16 + hi * 8;
      float4 ga = *(const float4*)(grow + d0);
      float4 gb = *(const float4*)(grow + d0 + 4);
      a[0] = (short)f2bf(ga.x); a[1] = (short)f2bf(ga.y);
      a[2] = (short)f2bf(ga.z); a[3] = (short)f2bf(ga.w);
      a[4] = (short)f2bf(gb.x); a[5] = (short)f2bf(gb.y);
      a[6] = (short)f2bf(gb.z); a[7] = (short)f2bf(gb.w);
    }
    if (o < DOUT) bf = *(const short8*)(Bcat + (size_t)o * BK + ks * 16 + hi * 8);
    else { short8 zz = {}; bf = zz; }
    if (ks & 1) acc1 = __builtin_amdgcn_mfma_f32_32x32x16_bf16(a, bf, acc1, 0, 0, 0);
    else        acc0 = __builtin_amdgcn_mfma_f32_32x32x16_bf16(a, bf, acc0, 0, 0, 0);
  }

  if (o < DOUT) {
    #pragma unroll
    for (int r = 0; r < 16; ++r) {
      int row = (r & 3) + 8 * (r >> 2) + 4 * hi;
      int i = i0 + row;
      if (i < N) {
        float h = src[i * DOUT + o] + (acc0[r] + acc1[r]) / Zsum[i];
        out[i * DOUT + o] = h > 0.f ? h : expm1f(h);
      }
    }
  }
}

extern "C" void kernel_launch(void* const* d_in, const int* in_sizes, int n_in,
                              void* d_out, int out_size, void* d_ws, size_t ws_size,
                              hipStream_t stream) {
  const float* R   = (const float*)d_in[0];
  const float* E   = (const float*)d_in[1];
  const int*   adj = (const int*)d_in[2];
  const float* A   = (const float*)d_in[3];
  const float* a2  = (const float*)d_in[4];
  float* out = (float*)d_out;

  char* wsb = (char*)d_ws;
  float*          src  = (float*)(wsb + 0);                // 200,000 B
  float*          ssrc = (float*)(wsb + 200000);           //   2,000 B
  float*          sdst = (float*)(wsb + 202000);           //   2,000 B
  float*          wv   = (float*)(wsb + 204000);           //     800 B
  unsigned short* Bcat = (unsigned short*)(wsb + 204800);  // 144,000 B
  unsigned short* Pbuf = (unsigned short*)(wsb + 348800);  // 512,000 B
  float*          gsum = (float*)(wsb + 860800);           // 416,000 B (f32, atomic)
  float*          Zsum = (float*)(wsb + 1276800);          //   2,000 B

  setup_kernel<<<704, 256, 0, stream>>>(R, A, a2, src, ssrc, sdst, wv, Bcat, Pbuf, gsum, Zsum);
  passA<<<N * JCH, 256, 0, stream>>>(E, adj, ssrc, sdst, wv, Pbuf, gsum, Zsum);
  combine_kernel<<<64, 64, 0, stream>>>(src, Pbuf, Bcat, gsum, Zsum, out);
}